// Round 1
// baseline (207.074 us; speedup 1.0000x reference)
//
#include <hip/hip_runtime.h>
#include <cstdint>

// Linear-chain CRF log-partition, B=64, T=4096, S=64.
// Strategy: probability-space recursion (matvec + emission scale) with
// chunked scan: C=64 chunks/batch; fwd pass y^T = 1^T M_c and bwd pass
// z = M_c 1 per chunk run fully in parallel (8192 independent wave-chains),
// combined under rank-1 chunk approximation (error ~ (lam2/lam1)^64 ~ 0).

#define BATCH 64
#define TLEN  4096
#define NS    64
#define NC    64                 // chunks per batch
#define CHAINS (BATCH*NC)        // 4096

__global__ __launch_bounds__(256) void crf_phase1(
    const float* __restrict__ scores,      // (B,T,S)
    const float* __restrict__ transition,  // (S,S) [from,to]
    float* __restrict__ Ybuf,              // (CHAINS, S) normalized y_c
    float* __restrict__ Zbuf,              // (CHAINS, S) normalized z_c
    float* __restrict__ Lz)                // (CHAINS,) log2 scale of z_c
{
    // union layout: fwd uses et[i*64+j]; bwd uses etT[j*65+i] (padded, conflict-free)
    __shared__ __align__(16) float et[64 * 65];
    __shared__ __align__(16) float ubuf[4][64];

    const int tid  = threadIdx.x;
    const int wave = tid >> 6;
    const int lane = tid & 63;
    const bool bwd = blockIdx.x >= (CHAINS / 4);
    const float LOG2E = 1.44269504088896340736f;

    // stage E = exp(transition) into LDS (layout depends on flavor)
    for (int idx = tid; idx < 64 * 64; idx += 256) {
        float ev = exp2f(transition[idx] * LOG2E);  // exp(x)
        int i = idx >> 6, j = idx & 63;
        if (!bwd) et[i * 64 + j] = ev;   // fwd: column j read per lane
        else      et[j * 65 + i] = ev;   // bwd: row i read per lane
    }
    __syncthreads();

    // per-lane E fragment in registers (64 VGPRs)
    float e[64];
    if (!bwd) {
        #pragma unroll
        for (int i = 0; i < 64; ++i) e[i] = et[i * 64 + lane];  // E[i][lane]
    } else {
        #pragma unroll
        for (int j = 0; j < 64; ++j) e[j] = et[j * 65 + lane];  // E[lane][j]
    }

    const int chain = (bwd ? (int)blockIdx.x - CHAINS / 4 : (int)blockIdx.x) * 4 + wave;
    const int b  = chain >> 6;
    const int c  = chain & 63;
    const int t0 = 1 + 64 * c;
    const int t1 = (t0 + 64 < TLEN) ? (t0 + 64) : TLEN;  // last chunk has 63 steps

    int   Ltot = 0;
    float v    = 1.0f;

    if (!bwd) {
        // y_{t}   : y' [j] = (sum_i y[i] E[i][j]) * s_t[j]
        const float* sp = scores + ((size_t)b * TLEN + t0) * NS + lane;
        float s_next = *sp;
        for (int t = t0; t < t1; ++t) {
            float sc = s_next;
            sp += NS;
            if (t + 1 < t1) s_next = *sp;   // uniform branch, prefetch
            ubuf[wave][lane] = v;
            __builtin_amdgcn_wave_barrier();
            float a0 = 0.f, a1 = 0.f, a2 = 0.f, a3 = 0.f;
            #pragma unroll
            for (int i = 0; i < 64; i += 4) {
                float4 u = *(const float4*)&ubuf[wave][i];  // broadcast read
                a0 = fmaf(u.x, e[i + 0], a0);
                a1 = fmaf(u.y, e[i + 1], a1);
                a2 = fmaf(u.z, e[i + 2], a2);
                a3 = fmaf(u.w, e[i + 3], a3);
            }
            float acc = (a0 + a1) + (a2 + a3);
            acc *= exp2f(sc * LOG2E);
            // renormalize by lane-0 exponent (exact pow2, no rounding)
            int rf = __builtin_amdgcn_readfirstlane(__float_as_int(acc));
            int ex = ((rf >> 23) & 255) - 127;
            acc *= __int_as_float((127 - ex) << 23);
            Ltot += ex;
            v = acc;
        }
        Ybuf[(size_t)chain * NS + lane] = v;   // Ly cancels algebraically; not stored
    } else {
        // z_{t-1}[i] = sum_j E[i][j] * s_t[j] * z_t[j]
        const float* sp = scores + ((size_t)b * TLEN + (t1 - 1)) * NS + lane;
        float s_next = *sp;
        for (int t = t1 - 1; t >= t0; --t) {
            float sc = s_next;
            sp -= NS;
            if (t - 1 >= t0) s_next = *sp;
            float w = exp2f(sc * LOG2E) * v;
            ubuf[wave][lane] = w;
            __builtin_amdgcn_wave_barrier();
            float a0 = 0.f, a1 = 0.f, a2 = 0.f, a3 = 0.f;
            #pragma unroll
            for (int j = 0; j < 64; j += 4) {
                float4 u = *(const float4*)&ubuf[wave][j];  // broadcast read
                a0 = fmaf(u.x, e[j + 0], a0);
                a1 = fmaf(u.y, e[j + 1], a1);
                a2 = fmaf(u.z, e[j + 2], a2);
                a3 = fmaf(u.w, e[j + 3], a3);
            }
            float acc = (a0 + a1) + (a2 + a3);
            int rf = __builtin_amdgcn_readfirstlane(__float_as_int(acc));
            int ex = ((rf >> 23) & 255) - 127;
            acc *= __int_as_float((127 - ex) << 23);
            Ltot += ex;
            v = acc;
        }
        Zbuf[(size_t)chain * NS + lane] = v;
        if (lane == 0) Lz[chain] = (float)Ltot;
    }
}

__device__ __forceinline__ float wsum64(float v) {
    #pragma unroll
    for (int m = 32; m >= 1; m >>= 1) v += __shfl_xor(v, m, 64);
    return v;
}

__global__ __launch_bounds__(64) void crf_phase2(
    const float* __restrict__ scores,
    const float* __restrict__ source,
    const float* __restrict__ sink,
    const float* __restrict__ Ybuf,
    const float* __restrict__ Zbuf,
    const float* __restrict__ Lz,
    float* __restrict__ out)
{
    const int b = blockIdx.x;
    const int j = threadIdx.x;   // one wave, lane per state; NC==64 too

    // sum of all chunk log2-scales (one Lz per lane since NC==64)
    float log2Z = wsum64(Lz[b * NC + j]);

    // a0 = exp(source + scores[:,0])  (the +log S of the reference added at end)
    float a0 = expf(source[j] + scores[(size_t)b * TLEN * NS + j]);
    float z0 = Zbuf[((size_t)b * NC + 0) * NS + j];
    log2Z += log2f(wsum64(a0 * z0));

    float esink = expf(sink[j]);
    for (int c = 0; c < NC; ++c) {
        float yh = Ybuf[((size_t)b * NC + c) * NS + j];
        float nx = (c < NC - 1) ? Zbuf[((size_t)b * NC + c + 1) * NS + j] : esink;
        float p = wsum64(yh * nx);
        float q = wsum64(yh);          // S_c = 1^T M_c 1 (up to cancelled scale)
        log2Z += log2f(p) - log2f(q);
    }
    if (j == 0)
        out[b] = 0.69314718055994530942f * log2Z + 4.15888308335967185707f; // ln2*log2Z + ln(64)
}

extern "C" void kernel_launch(void* const* d_in, const int* in_sizes, int n_in,
                              void* d_out, int out_size, void* d_ws, size_t ws_size,
                              hipStream_t stream) {
    (void)in_sizes; (void)n_in; (void)out_size; (void)ws_size;
    const float* scores     = (const float*)d_in[0];
    const float* transition = (const float*)d_in[1];
    const float* source     = (const float*)d_in[2];
    const float* sink       = (const float*)d_in[3];
    float* out = (float*)d_out;

    float* Ybuf = (float*)d_ws;                          // CHAINS*NS floats (1 MB)
    float* Zbuf = Ybuf + (size_t)CHAINS * NS;            // CHAINS*NS floats (1 MB)
    float* Lz   = Zbuf + (size_t)CHAINS * NS;            // CHAINS floats (16 KB)

    hipLaunchKernelGGL(crf_phase1, dim3(2 * (CHAINS / 4)), dim3(256), 0, stream,
                       scores, transition, Ybuf, Zbuf, Lz);
    hipLaunchKernelGGL(crf_phase2, dim3(BATCH), dim3(64), 0, stream,
                       scores, source, sink, Ybuf, Zbuf, Lz, out);
}

// Round 2
// 150.858 us; speedup vs baseline: 1.3726x; 1.3726x over previous
//
#include <hip/hip_runtime.h>
#include <cstdint>

// Linear-chain CRF log-partition, B=64, T=4096, S=64.
// R2: MFMA rewrite. Chunked scan (NC=117 chunks of L=35 steps, 117*35=4095),
// fwd y^T = 1^T M_c and bwd z = M_c 1 per chunk, rank-1 recombination.
// 16 chains per wave via mfma_f32_16x16x32_bf16; emissions pre-exp'd and
// pre-swizzled into C-fragment order by a prep kernel (bf16, 36.7 MB in d_ws).

#define B_    64
#define T_    4096
#define S_    64
#define L_    35                  // steps per chunk
#define NC_   117                 // chunks per batch (117*35 == 4095)
#define CPB_  128                 // padded chains per batch (8 waves * 16)
#define WPB_  8                   // wave-groups per batch per direction
#define NTILE_ (B_ * WPB_ * L_)   // 17920 emission tiles (2 KB each)
#define LOG2E 1.44269504088896340736f

typedef float  f32x4  __attribute__((ext_vector_type(4)));
typedef __bf16 bf16x8 __attribute__((ext_vector_type(8)));

union U4B { uint4 u; bf16x8 b; };

__device__ __forceinline__ unsigned rne_bf16(float f) {
    unsigned x = __float_as_uint(f);
    return (x + 0x7FFFu + ((x >> 16) & 1u)) >> 16;
}

// ---------------------------------------------------------------------------
// prep: P4[tile=(b,g8,tt)][lane][j] = bf16(exp(scores)), fragment-ordered.
// tile (b,g8,tt): chain m=0..15 -> chunk c=16*g8+m, global t = 1 + 35c + tt.
// lane (g=lane>>4,l=lane&15), j=4*nt+r -> value (chain 4g+r, state 16nt+l).
// ---------------------------------------------------------------------------
__global__ __launch_bounds__(256) void crf_prep(
    const float* __restrict__ scores, unsigned short* __restrict__ P4)
{
    __shared__ float tile[4][16][65];
    const int wl   = threadIdx.x >> 6;
    const int lane = threadIdx.x & 63;
    const int wid  = blockIdx.x * 4 + wl;          // 0..17919
    const int b  = wid / (WPB_ * L_);
    const int r0 = wid % (WPB_ * L_);
    const int g8 = r0 / L_;
    const int tt = r0 % L_;

    #pragma unroll
    for (int m = 0; m < 16; ++m) {
        int c = g8 * 16 + m;
        float v = 0.0f;                            // pad chains: score 0 -> em 1
        if (c < NC_) v = scores[((size_t)b * T_ + (1 + L_ * c + tt)) * S_ + lane];
        tile[wl][m][lane] = v;
    }
    __builtin_amdgcn_s_waitcnt(0xC07F);            // lgkmcnt(0) only
    __builtin_amdgcn_wave_barrier();

    const int g = lane >> 4, l = lane & 15;
    unsigned out[8];
    #pragma unroll
    for (int d = 0; d < 8; ++d) {
        int j0 = 2 * d, j1 = 2 * d + 1;
        float f0 = exp2f(tile[wl][4 * g + (j0 & 3)][16 * (j0 >> 2) + l] * LOG2E);
        float f1 = exp2f(tile[wl][4 * g + (j1 & 3)][16 * (j1 >> 2) + l] * LOG2E);
        out[d] = rne_bf16(f0) | (rne_bf16(f1) << 16);
    }
    uint4* dst = (uint4*)(P4 + (size_t)wid * 1024) + lane * 2;
    dst[0] = make_uint4(out[0], out[1], out[2], out[3]);
    dst[1] = make_uint4(out[4], out[5], out[6], out[7]);
}

// ---------------------------------------------------------------------------
// phase1: one wave per (direction, b, g8); 16 chains via MFMA.
// fwd:  u <- (u * E) .* em      (u starts at ones; 35 steps ascending)
// bwd:  z <- E * (em .* z)      (z starts at ones; 35 steps descending)
// ---------------------------------------------------------------------------
__global__ __launch_bounds__(64, 2) void crf_phase1(
    const float* __restrict__ transition,
    const unsigned short* __restrict__ P4,
    float* __restrict__ Ybuf, float* __restrict__ Zbuf, float* __restrict__ Lz)
{
    __shared__ float tb[2][16][68];
    const int w   = blockIdx.x;
    const bool bwd = w >= (B_ * WPB_);
    const int wg  = bwd ? w - B_ * WPB_ : w;
    const int b   = wg >> 3;
    const int g8  = wg & 7;
    const int lane = threadIdx.x;
    const int g = lane >> 4, l = lane & 15;

    // ---- E fragments (register-resident, 32 VGPRs) ----
    // fwd: B[k][n] = exp(T[k][n]);  bwd: B[k][n] = exp(T[n][k])  (E^T)
    bf16x8 BE[2][4];
    #pragma unroll
    for (int kb = 0; kb < 2; ++kb)
    #pragma unroll
    for (int nt = 0; nt < 4; ++nt) {
        unsigned pk[4];
        #pragma unroll
        for (int dd = 0; dd < 4; ++dd) {
            int k0 = 32 * kb + 8 * g + 2 * dd;
            int n  = 16 * nt + l;
            float e0, e1;
            if (!bwd) { e0 = transition[k0 * 64 + n]; e1 = transition[(k0 + 1) * 64 + n]; }
            else      { e0 = transition[n * 64 + k0]; e1 = transition[n * 64 + k0 + 1]; }
            pk[dd] = rne_bf16(exp2f(e0 * LOG2E)) | (rne_bf16(exp2f(e1 * LOG2E)) << 16);
        }
        U4B t; t.u = make_uint4(pk[0], pk[1], pk[2], pk[3]);
        BE[kb][nt] = t.b;
    }

    const size_t tbase = (size_t)(b * WPB_ + g8) * L_;
    const uint4* tp = (const uint4*)P4;

    f32x4 acc[4];
    #pragma unroll
    for (int nt = 0; nt < 4; ++nt) acc[nt] = {1.f, 1.f, 1.f, 1.f};
    int Lt[4] = {0, 0, 0, 0};

    auto ldtile = [&](int tt, uint4& x, uint4& y) {
        const uint4* p = tp + (tbase + tt) * 128 + lane * 2;
        x = p[0]; y = p[1];
    };
    auto emmul = [&](const uint4& c0, const uint4& c1) {
        unsigned dw[8] = {c0.x, c0.y, c0.z, c0.w, c1.x, c1.y, c1.z, c1.w};
        #pragma unroll
        for (int nt = 0; nt < 4; ++nt)
            #pragma unroll
            for (int r = 0; r < 4; ++r) {
                unsigned d = dw[2 * nt + (r >> 1)];
                float em = (r & 1) ? __uint_as_float(d & 0xFFFF0000u)
                                   : __uint_as_float(d << 16);
                acc[nt][r] *= em;
            }
    };
    auto renorm = [&]() {
        #pragma unroll
        for (int r = 0; r < 4; ++r) {
            float m = fmaxf(fmaxf(acc[0][r], acc[1][r]), fmaxf(acc[2][r], acc[3][r]));
            m = fmaxf(m, __shfl_xor(m, 1, 64));
            m = fmaxf(m, __shfl_xor(m, 2, 64));
            m = fmaxf(m, __shfl_xor(m, 4, 64));
            m = fmaxf(m, __shfl_xor(m, 8, 64));
            int ex = (int)(__float_as_uint(m) >> 23) - 127;
            float sc = __uint_as_float((unsigned)(127 - ex) << 23);   // exact 2^-ex
            Lt[r] += ex;
            #pragma unroll
            for (int nt = 0; nt < 4; ++nt) acc[nt][r] *= sc;
        }
    };
    auto transpose_mfma = [&](int buf) {
        #pragma unroll
        for (int nt = 0; nt < 4; ++nt)
            #pragma unroll
            for (int r = 0; r < 4; ++r)
                tb[buf][4 * g + r][16 * nt + l] = acc[nt][r];
        __builtin_amdgcn_s_waitcnt(0xC07F);        // lgkmcnt(0); keep vmcnt open
        __builtin_amdgcn_wave_barrier();
        bf16x8 A[2];
        #pragma unroll
        for (int kb = 0; kb < 2; ++kb) {
            const float* rowp = &tb[buf][l][32 * kb + 8 * g];
            float4 x = *(const float4*)rowp;
            float4 y = *(const float4*)(rowp + 4);
            U4B t;
            t.u.x = (__float_as_uint(x.x) >> 16) | (__float_as_uint(x.y) & 0xFFFF0000u);
            t.u.y = (__float_as_uint(x.z) >> 16) | (__float_as_uint(x.w) & 0xFFFF0000u);
            t.u.z = (__float_as_uint(y.x) >> 16) | (__float_as_uint(y.y) & 0xFFFF0000u);
            t.u.w = (__float_as_uint(y.z) >> 16) | (__float_as_uint(y.w) & 0xFFFF0000u);
            A[kb] = t.b;
        }
        #pragma unroll
        for (int nt = 0; nt < 4; ++nt) {
            f32x4 z4 = {0.f, 0.f, 0.f, 0.f};
            z4      = __builtin_amdgcn_mfma_f32_16x16x32_bf16(A[0], BE[0][nt], z4, 0, 0, 0);
            acc[nt] = __builtin_amdgcn_mfma_f32_16x16x32_bf16(A[1], BE[1][nt], z4, 0, 0, 0);
        }
    };

    if (!bwd) {
        uint4 pa0, pb0, pa1, pb1;
        ldtile(0, pa0, pb0);
        ldtile(1, pa1, pb1);
        for (int tt = 0; tt < L_; ++tt) {
            uint4 c0 = pa0, c1 = pb0;
            pa0 = pa1; pb0 = pb1;
            int tn = tt + 2; if (tn > L_ - 1) tn = L_ - 1;
            ldtile(tn, pa1, pb1);
            transpose_mfma(tt & 1);
            emmul(c0, c1);
            if ((tt & 3) == 3) renorm();
        }
        float* yb = Ybuf + ((size_t)b * CPB_ + g8 * 16) * 64;
        #pragma unroll
        for (int nt = 0; nt < 4; ++nt)
            #pragma unroll
            for (int r = 0; r < 4; ++r)
                yb[(4 * g + r) * 64 + 16 * nt + l] = acc[nt][r];
    } else {
        uint4 pa0, pb0, pa1, pb1;
        ldtile(L_ - 1, pa0, pb0);
        ldtile(L_ - 2, pa1, pb1);
        for (int i = 0; i < L_; ++i) {
            uint4 c0 = pa0, c1 = pb0;
            pa0 = pa1; pb0 = pb1;
            int tn = L_ - 1 - i - 2; if (tn < 0) tn = 0;
            ldtile(tn, pa1, pb1);
            emmul(c0, c1);
            if ((i & 3) == 3) renorm();
            transpose_mfma(i & 1);
        }
        float* zb = Zbuf + ((size_t)b * CPB_ + g8 * 16) * 64;
        #pragma unroll
        for (int nt = 0; nt < 4; ++nt)
            #pragma unroll
            for (int r = 0; r < 4; ++r)
                zb[(4 * g + r) * 64 + 16 * nt + l] = acc[nt][r];
        if (l == 0) {
            #pragma unroll
            for (int r = 0; r < 4; ++r)
                Lz[b * CPB_ + g8 * 16 + 4 * g + r] = (float)Lt[r];
        }
    }
}

// ---------------------------------------------------------------------------
// phase2: rank-1 recombination, chunk-parallel.
// log2 Z = sum_c Lz[c] + log2(a0.z_0) + sum_c [log2(y_c.nx_c) - log2(y_c.1)]
// ---------------------------------------------------------------------------
__global__ __launch_bounds__(256) void crf_phase2(
    const float* __restrict__ scores, const float* __restrict__ source,
    const float* __restrict__ sink,
    const float* __restrict__ Ybuf, const float* __restrict__ Zbuf,
    const float* __restrict__ Lz, float* __restrict__ out)
{
    __shared__ float part[4];
    const int b = blockIdx.x;
    const int wv = threadIdx.x >> 6;
    const int lane = threadIdx.x & 63;
    const float esink = exp2f(sink[lane] * LOG2E);

    float acc = 0.f;
    for (int c = wv; c < NC_; c += 4) {
        float yh = Ybuf[((size_t)b * CPB_ + c) * 64 + lane];
        float nx = (c < NC_ - 1) ? Zbuf[((size_t)b * CPB_ + c + 1) * 64 + lane] : esink;
        float p = yh * nx, q = yh;
        #pragma unroll
        for (int m = 32; m >= 1; m >>= 1) {
            p += __shfl_xor(p, m, 64);
            q += __shfl_xor(q, m, 64);
        }
        acc += log2f(p) - log2f(q) + Lz[b * CPB_ + c];
    }
    if (wv == 0) {
        float a0 = exp2f((source[lane] + scores[(size_t)b * T_ * S_ + lane]) * LOG2E);
        float p = a0 * Zbuf[((size_t)b * CPB_) * 64 + lane];
        #pragma unroll
        for (int m = 32; m >= 1; m >>= 1) p += __shfl_xor(p, m, 64);
        acc += log2f(p);
    }
    if (lane == 0) part[wv] = acc;
    __syncthreads();
    if (threadIdx.x == 0)
        out[b] = 0.6931471805599453f * (part[0] + part[1] + part[2] + part[3])
               + 4.158883083359672f;   // ln2 * log2Z + ln(64)
}

extern "C" void kernel_launch(void* const* d_in, const int* in_sizes, int n_in,
                              void* d_out, int out_size, void* d_ws, size_t ws_size,
                              hipStream_t stream) {
    (void)in_sizes; (void)n_in; (void)out_size; (void)ws_size;
    const float* scores     = (const float*)d_in[0];
    const float* transition = (const float*)d_in[1];
    const float* source     = (const float*)d_in[2];
    const float* sink       = (const float*)d_in[3];
    float* out = (float*)d_out;

    unsigned short* P4 = (unsigned short*)d_ws;                       // 36.7 MB
    float* Ybuf = (float*)((char*)d_ws + (size_t)NTILE_ * 2048);      // 2 MB
    float* Zbuf = Ybuf + (size_t)B_ * CPB_ * 64;                      // 2 MB
    float* Lz   = Zbuf + (size_t)B_ * CPB_ * 64;                      // 32 KB

    hipLaunchKernelGGL(crf_prep,   dim3(NTILE_ / 4), dim3(256), 0, stream, scores, P4);
    hipLaunchKernelGGL(crf_phase1, dim3(2 * B_ * WPB_), dim3(64), 0, stream,
                       transition, P4, Ybuf, Zbuf, Lz);
    hipLaunchKernelGGL(crf_phase2, dim3(B_), dim3(256), 0, stream,
                       scores, source, sink, Ybuf, Zbuf, Lz, out);
}

// Round 3
// 138.013 us; speedup vs baseline: 1.5004x; 1.0931x over previous
//
#include <hip/hip_runtime.h>
#include <cstdint>

// Linear-chain CRF log-partition, B=64, T=4096, S=64.
// R3: no prep kernel. Chunked scan NC=273 x L=15 (273*15=4095), fwd/bwd
// chunk maps via mfma_f32_16x16x32_bf16 (16 chains/wave), rank-1 recombine.
// Emissions applied in A-operand layout (contiguous -> float4 global loads,
// fp32 precision), transpose C->A through per-wave LDS, 2.25 waves/SIMD.

#define B_    64
#define T_    4096
#define S_    64
#define L_    15
#define NC_   273                 // 273*15 = 4095 = T_-1
#define WPB_  18                  // ceil(273/16) waves per batch per direction
#define CPB_  288                 // padded chains per batch
#define LOG2E 1.44269504088896340736f

typedef float  f32x4  __attribute__((ext_vector_type(4)));
typedef __bf16 bf16x8 __attribute__((ext_vector_type(8)));
union U4B { uint4 u; bf16x8 b; };

__device__ __forceinline__ unsigned rne_bf16(float f) {
    unsigned x = __float_as_uint(f);
    return (x + 0x7FFFu + ((x >> 16) & 1u)) >> 16;
}
__device__ __forceinline__ unsigned pk2(float a, float b) {
    return rne_bf16(a) | (rne_bf16(b) << 16);
}

__global__ __launch_bounds__(64, 3) void crf_phase1(
    const float* __restrict__ scores,      // (B,T,S)
    const float* __restrict__ transition,  // (S,S) [from,to]
    float* __restrict__ Ybuf, float* __restrict__ Zbuf, float* __restrict__ Lz)
{
    __shared__ float tb[2][16][68];
    const int wid  = blockIdx.x;
    const bool bwd = wid >= (B_ * WPB_);
    const int wl   = bwd ? wid - B_ * WPB_ : wid;
    const int b    = wl / WPB_, wg = wl % WPB_;
    const int lane = threadIdx.x, g = lane >> 4, l = lane & 15;

    // ---- E fragments in registers: fwd B[k][n]=exp(T[k][n]); bwd =exp(T[n][k])
    bf16x8 BE[2][4];
    #pragma unroll
    for (int kb = 0; kb < 2; ++kb)
    #pragma unroll
    for (int nt = 0; nt < 4; ++nt) {
        unsigned pk[4];
        #pragma unroll
        for (int dd = 0; dd < 4; ++dd) {
            int k0 = 32 * kb + 8 * g + 2 * dd, n = 16 * nt + l;
            float e0, e1;
            if (!bwd) { e0 = transition[k0 * 64 + n]; e1 = transition[(k0 + 1) * 64 + n]; }
            else      { e0 = transition[n * 64 + k0]; e1 = transition[n * 64 + k0 + 1]; }
            pk[dd] = pk2(exp2f(e0 * LOG2E), exp2f(e1 * LOG2E));
        }
        U4B t; t.u = make_uint4(pk[0], pk[1], pk[2], pk[3]); BE[kb][nt] = t.b;
    }

    // A-side emission pointer: chain = local row l, states 8g.. contiguous
    int cl = 16 * wg + l; if (cl > NC_ - 1) cl = NC_ - 1;
    const float* ap = scores + ((size_t)b * T_ + 15 * cl + (bwd ? 15 : 0)) * S_ + 8 * g;

    f32x4 acc[4];
    int Lt[4] = {0, 0, 0, 0};

    auto mfma8 = [&](bf16x8 A0, bf16x8 A1) {
        #pragma unroll
        for (int nt = 0; nt < 4; ++nt) {
            f32x4 z4 = {0.f, 0.f, 0.f, 0.f};
            z4      = __builtin_amdgcn_mfma_f32_16x16x32_bf16(A0, BE[0][nt], z4, 0, 0, 0);
            acc[nt] = __builtin_amdgcn_mfma_f32_16x16x32_bf16(A1, BE[1][nt], z4, 0, 0, 0);
        }
    };
    auto renorm = [&]() {
        #pragma unroll
        for (int r = 0; r < 4; ++r) {
            float m = fmaxf(fmaxf(acc[0][r], acc[1][r]), fmaxf(acc[2][r], acc[3][r]));
            m = fmaxf(m, __shfl_xor(m, 1, 64));
            m = fmaxf(m, __shfl_xor(m, 2, 64));
            m = fmaxf(m, __shfl_xor(m, 4, 64));
            m = fmaxf(m, __shfl_xor(m, 8, 64));
            int ex = (int)(__float_as_uint(m) >> 23) - 127;
            float sc = __uint_as_float((unsigned)(127 - ex) << 23);   // exact 2^-ex
            Lt[r] += ex;
            #pragma unroll
            for (int nt = 0; nt < 4; ++nt) acc[nt][r] *= sc;
        }
    };
    // transpose acc (C: chain 4g+r, state 16nt+l) -> per-lane A rows, * em, pack
    auto xposeA = [&](int par, const f32x4& c0, const f32x4& c1,
                      const f32x4& c2, const f32x4& c3, bf16x8& A0, bf16x8& A1) {
        float (*tp)[68] = tb[par];
        #pragma unroll
        for (int nt = 0; nt < 4; ++nt)
            #pragma unroll
            for (int r = 0; r < 4; ++r)
                tp[4 * g + r][16 * nt + l] = acc[nt][r];
        __builtin_amdgcn_s_waitcnt(0xC07F);        // lgkmcnt(0) only
        __builtin_amdgcn_wave_barrier();
        const float* rowp = &tp[l][8 * g];
        f32x4 x0 = *(const f32x4*)rowp;
        f32x4 x1 = *(const f32x4*)(rowp + 4);
        f32x4 x2 = *(const f32x4*)(rowp + 32);
        f32x4 x3 = *(const f32x4*)(rowp + 36);
        U4B t0, t1;
        t0.u.x = pk2(x0[0] * exp2f(c0[0] * LOG2E), x0[1] * exp2f(c0[1] * LOG2E));
        t0.u.y = pk2(x0[2] * exp2f(c0[2] * LOG2E), x0[3] * exp2f(c0[3] * LOG2E));
        t0.u.z = pk2(x1[0] * exp2f(c1[0] * LOG2E), x1[1] * exp2f(c1[1] * LOG2E));
        t0.u.w = pk2(x1[2] * exp2f(c1[2] * LOG2E), x1[3] * exp2f(c1[3] * LOG2E));
        t1.u.x = pk2(x2[0] * exp2f(c2[0] * LOG2E), x2[1] * exp2f(c2[1] * LOG2E));
        t1.u.y = pk2(x2[2] * exp2f(c2[2] * LOG2E), x2[3] * exp2f(c2[3] * LOG2E));
        t1.u.z = pk2(x3[0] * exp2f(c3[0] * LOG2E), x3[1] * exp2f(c3[1] * LOG2E));
        t1.u.w = pk2(x3[2] * exp2f(c3[2] * LOG2E), x3[3] * exp2f(c3[3] * LOG2E));
        A0 = t0.b; A1 = t1.b;
    };
    auto ldq = [&](int idx, f32x4& q0, f32x4& q1, f32x4& q2, f32x4& q3) {
        const float* p = ap + (ptrdiff_t)idx * S_;
        q0 = *(const f32x4*)p;        q1 = *(const f32x4*)(p + 4);
        q2 = *(const f32x4*)(p + 32); q3 = *(const f32x4*)(p + 36);
    };

    if (!bwd) {
        // v_{tt+1} = (v_tt E) .* em_{t0+tt}; em folded into next step's A.
        f32x4 q0, q1, q2, q3;
        ldq(1, q0, q1, q2, q3);                    // em for A-step tt=1
        { U4B t; t.u = make_uint4(0x3F803F80u, 0x3F803F80u, 0x3F803F80u, 0x3F803F80u);
          mfma8(t.b, t.b); }                       // tt=0: A = ones
        #pragma unroll 2
        for (int tt = 1; tt < L_; ++tt) {
            f32x4 c0 = q0, c1 = q1, c2 = q2, c3 = q3;
            if (tt + 1 < L_) ldq(tt + 1, q0, q1, q2, q3);
            bf16x8 A0, A1;
            xposeA(tt & 1, c0, c1, c2, c3, A0, A1);
            mfma8(A0, A1);
            if ((tt & 3) == 3) renorm();
        }
        // trailing emission (t = 15c+15) applied in C layout, then store y
        #pragma unroll
        for (int r = 0; r < 4; ++r) {
            int c = 16 * wg + 4 * g + r; int cc = c > NC_ - 1 ? NC_ - 1 : c;
            const float* bp = scores + ((size_t)b * T_ + 15 * cc + 15) * S_ + l;
            float* yb = Ybuf + ((size_t)b * CPB_ + c) * S_ + l;
            #pragma unroll
            for (int nt = 0; nt < 4; ++nt)
                yb[16 * nt] = acc[nt][r] * exp2f(bp[16 * nt] * LOG2E);
        }
    } else {
        // z_{i+1} = E (em_{t1-1-i} .* z_i); em applied on A side each step.
        f32x4 q0, q1, q2, q3, n0, n1, n2, n3;
        ldq(0, q0, q1, q2, q3);
        ldq(-1, n0, n1, n2, n3);
        {   // i=0: A = em (z=ones)
            U4B t0, t1;
            t0.u.x = pk2(exp2f(q0[0] * LOG2E), exp2f(q0[1] * LOG2E));
            t0.u.y = pk2(exp2f(q0[2] * LOG2E), exp2f(q0[3] * LOG2E));
            t0.u.z = pk2(exp2f(q1[0] * LOG2E), exp2f(q1[1] * LOG2E));
            t0.u.w = pk2(exp2f(q1[2] * LOG2E), exp2f(q1[3] * LOG2E));
            t1.u.x = pk2(exp2f(q2[0] * LOG2E), exp2f(q2[1] * LOG2E));
            t1.u.y = pk2(exp2f(q2[2] * LOG2E), exp2f(q2[3] * LOG2E));
            t1.u.z = pk2(exp2f(q3[0] * LOG2E), exp2f(q3[1] * LOG2E));
            t1.u.w = pk2(exp2f(q3[2] * LOG2E), exp2f(q3[3] * LOG2E));
            mfma8(t0.b, t1.b);
        }
        #pragma unroll 2
        for (int i = 1; i < L_; ++i) {
            f32x4 c0 = n0, c1 = n1, c2 = n2, c3 = n3;
            if (i + 1 < L_) ldq(-(i + 1), n0, n1, n2, n3);
            bf16x8 A0, A1;
            xposeA(i & 1, c0, c1, c2, c3, A0, A1);
            mfma8(A0, A1);
            if ((i & 3) == 3) renorm();
        }
        #pragma unroll
        for (int r = 0; r < 4; ++r) {
            int c = 16 * wg + 4 * g + r;
            float* zb = Zbuf + ((size_t)b * CPB_ + c) * S_ + l;
            #pragma unroll
            for (int nt = 0; nt < 4; ++nt) zb[16 * nt] = acc[nt][r];
            if (l == 0) Lz[b * CPB_ + c] = (float)Lt[r];
        }
    }
}

// ---------------------------------------------------------------------------
// phase2: rank-1 recombination, chunk-parallel (8 waves / batch).
// log2 Z = sum_c Lz[c] + log2(a0.z_0) + sum_c [log2(y_c.nx_c) - log2(y_c.1)]
// ---------------------------------------------------------------------------
__global__ __launch_bounds__(512) void crf_phase2(
    const float* __restrict__ scores, const float* __restrict__ source,
    const float* __restrict__ sink,
    const float* __restrict__ Ybuf, const float* __restrict__ Zbuf,
    const float* __restrict__ Lz, float* __restrict__ out)
{
    __shared__ float part[8];
    const int b = blockIdx.x;
    const int wv = threadIdx.x >> 6, lane = threadIdx.x & 63;
    const float esink = exp2f(sink[lane] * LOG2E);

    float acc = 0.f;
    for (int c = wv; c < NC_; c += 8) {
        float yh = Ybuf[((size_t)b * CPB_ + c) * 64 + lane];
        float nx = (c < NC_ - 1) ? Zbuf[((size_t)b * CPB_ + c + 1) * 64 + lane] : esink;
        float p = yh * nx, q = yh;
        #pragma unroll
        for (int m = 32; m >= 1; m >>= 1) {
            p += __shfl_xor(p, m, 64);
            q += __shfl_xor(q, m, 64);
        }
        acc += log2f(p) - log2f(q) + Lz[b * CPB_ + c];
    }
    if (wv == 0) {
        float a0 = exp2f((source[lane] + scores[(size_t)b * T_ * S_ + lane]) * LOG2E);
        float p = a0 * Zbuf[((size_t)b * CPB_) * 64 + lane];
        #pragma unroll
        for (int m = 32; m >= 1; m >>= 1) p += __shfl_xor(p, m, 64);
        acc += log2f(p);
    }
    if (lane == 0) part[wv] = acc;
    __syncthreads();
    if (threadIdx.x == 0) {
        float s = 0.f;
        #pragma unroll
        for (int i = 0; i < 8; ++i) s += part[i];
        out[b] = 0.6931471805599453f * s + 4.158883083359672f;  // ln2*log2Z + ln(64)
    }
}

extern "C" void kernel_launch(void* const* d_in, const int* in_sizes, int n_in,
                              void* d_out, int out_size, void* d_ws, size_t ws_size,
                              hipStream_t stream) {
    (void)in_sizes; (void)n_in; (void)out_size; (void)ws_size;
    const float* scores     = (const float*)d_in[0];
    const float* transition = (const float*)d_in[1];
    const float* source     = (const float*)d_in[2];
    const float* sink       = (const float*)d_in[3];
    float* out = (float*)d_out;

    float* Ybuf = (float*)d_ws;                          // B*CPB*64 floats (4.7 MB)
    float* Zbuf = Ybuf + (size_t)B_ * CPB_ * 64;         // 4.7 MB
    float* Lz   = Zbuf + (size_t)B_ * CPB_ * 64;         // 73 KB

    hipLaunchKernelGGL(crf_phase1, dim3(2 * B_ * WPB_), dim3(64), 0, stream,
                       scores, transition, Ybuf, Zbuf, Lz);
    hipLaunchKernelGGL(crf_phase2, dim3(B_), dim3(512), 0, stream,
                       scores, source, sink, Ybuf, Zbuf, Lz, out);
}